// Round 10
// baseline (430.526 us; speedup 1.0000x reference)
//
#include <hip/hip_runtime.h>
#include <hip/hip_bf16.h>

#define HD   768
#define BSZ  4
#define SEQ  2048
#define NTOK (BSZ*SEQ)   // 8192
#define NHD  12
#define DKD  64

typedef __bf16 bf16_t;
typedef __bf16 bf16x8 __attribute__((ext_vector_type(8)));
typedef __bf16 bf16x4 __attribute__((ext_vector_type(4)));
typedef float  f32x4  __attribute__((ext_vector_type(4)));

__device__ __forceinline__ void async16(const void* g, void* l) {
    __builtin_amdgcn_global_load_lds(
        (const __attribute__((address_space(1))) unsigned int*)g,
        (__attribute__((address_space(3))) unsigned int*)l, 16, 0, 0);
}

// ---- fused prep: LN1 (8192 blk) + 6 weight transposes (6912) + mask (32) ----
// wq is pre-scaled by 0.125*log2e so QK^T lands directly in log2 domain;
// mask bias likewise scaled by log2e (exp2 softmax).
__global__ __launch_bounds__(256) void prep_kernel(
    const float* __restrict__ x, const float* __restrict__ ln1_w,
    const float* __restrict__ ln1_b, bf16_t* __restrict__ y,
    const float* __restrict__ wq, const float* __restrict__ wk,
    const float* __restrict__ wv, const float* __restrict__ wo,
    const float* __restrict__ w1, const float* __restrict__ w2,
    const int* __restrict__ mask,
    bf16_t* __restrict__ wqkvT, bf16_t* __restrict__ woT,
    bf16_t* __restrict__ w1T, bf16_t* __restrict__ w2T,
    float* __restrict__ mb)
{
    const int bid = blockIdx.x, t = threadIdx.x;
    if (bid < 8192) {                        // ---- LN1 row ----
        const int row = bid;
        const float* xr = x + (size_t)row * HD;
        float v0 = xr[t], v1 = xr[t + 256], v2 = xr[t + 512];
        float s1 = v0 + v1 + v2;
        float s2 = v0*v0 + v1*v1 + v2*v2;
#pragma unroll
        for (int m = 1; m < 64; m <<= 1) {
            s1 += __shfl_xor(s1, m);
            s2 += __shfl_xor(s2, m);
        }
        __shared__ float red[8];
        const int w = t >> 6, l = t & 63;
        if (l == 0) { red[w] = s1; red[4 + w] = s2; }
        __syncthreads();
        s1 = red[0] + red[1] + red[2] + red[3];
        s2 = red[4] + red[5] + red[6] + red[7];
        float mean = s1 * (1.f/HD);
        float var  = fmaxf(s2 * (1.f/HD) - mean*mean, 0.f);
        float rstd = rsqrtf(var + 1e-12f);
        bf16_t* yr = y + (size_t)row * HD;
        yr[t]       = (bf16_t)(ln1_w[t]      * (v0 - mean) * rstd + ln1_b[t]);
        yr[t + 256] = (bf16_t)(ln1_w[t + 256]* (v1 - mean) * rstd + ln1_b[t + 256]);
        yr[t + 512] = (bf16_t)(ln1_w[t + 512]* (v2 - mean) * rstd + ln1_b[t + 512]);
        return;
    }
    const int wb = bid - 8192;
    if (wb >= 6912) {                        // ---- mask -> log2-domain bias ----
        const int i = (wb - 6912) * 256 + t;
        mb[i] = mask[i] ? 0.f : -1.4426950e9f;
        return;
    }
    const float* in; bf16_t* out; int K, N, ktile, ntile;
    float scale = 1.f;
    if (wb < 2304) {
        const int wsel = wb / 576, tt = wb % 576;
        const float* srcs[4] = { wq, wk, wv, wo };
        bf16_t* dsts[4] = { wqkvT, wqkvT + 768*768, wqkvT + 2*768*768, woT };
        in = srcs[wsel]; out = dsts[wsel]; K = 768; N = 768;
        if (wsel == 0) scale = 0.18033688f;  // 0.125 * log2(e)
        ktile = tt / 24; ntile = tt % 24;
    } else if (wb < 4608) {
        const int tt = wb - 2304;
        in = w1; out = w1T; K = 768; N = 3072;
        ktile = tt / 96; ntile = tt % 96;
    } else {
        const int tt = wb - 4608;
        in = w2; out = w2T; K = 3072; N = 768;
        ktile = tt / 24; ntile = tt % 24;
    }
    __shared__ float tile[32][33];
    const int k0 = ktile * 32, n0 = ntile * 32;
    const int r = t >> 5, c = t & 31;
#pragma unroll
    for (int j = 0; j < 4; j++)
        tile[r + 8*j][c] = in[(size_t)(k0 + r + 8*j) * N + n0 + c];
    __syncthreads();
#pragma unroll
    for (int j = 0; j < 4; j++)
        out[(size_t)(n0 + r + 8*j) * K + k0 + c] = (bf16_t)(tile[c][r + 8*j] * scale);
}

// ---------------- layernorm: f32 [rows][768] -> bf16 (LN2) -------------------
__global__ __launch_bounds__(256) void ln_kernel(
    const float* __restrict__ x, const float* __restrict__ gw,
    const float* __restrict__ gb, bf16_t* __restrict__ y)
{
    const int row = blockIdx.x, t = threadIdx.x;
    const float* xr = x + (size_t)row * HD;
    float v0 = xr[t], v1 = xr[t + 256], v2 = xr[t + 512];
    float s1 = v0 + v1 + v2;
    float s2 = v0*v0 + v1*v1 + v2*v2;
#pragma unroll
    for (int m = 1; m < 64; m <<= 1) {
        s1 += __shfl_xor(s1, m);
        s2 += __shfl_xor(s2, m);
    }
    __shared__ float red[8];
    const int w = t >> 6, l = t & 63;
    if (l == 0) { red[w] = s1; red[4 + w] = s2; }
    __syncthreads();
    s1 = red[0] + red[1] + red[2] + red[3];
    s2 = red[4] + red[5] + red[6] + red[7];
    float mean = s1 * (1.f/HD);
    float var  = fmaxf(s2 * (1.f/HD) - mean*mean, 0.f);
    float rstd = rsqrtf(var + 1e-12f);
    bf16_t* yr = y + (size_t)row * HD;
    yr[t]       = (bf16_t)(gw[t]      * (v0 - mean) * rstd + gb[t]);
    yr[t + 256] = (bf16_t)(gw[t + 256]* (v1 - mean) * rstd + gb[t + 256]);
    yr[t + 512] = (bf16_t)(gw[t + 512]* (v2 - mean) * rstd + gb[t + 512]);
}

// ---------------- GEMM: A[M][K] bf16 x BT[N][K] bf16 --------------------------
// depth-2 prefetch pipeline: 3 LDS buffers, counted vmcnt(4), 1 s_barrier/iter.
// EPI 0: bf16 store.           EPI 1: f32 store + bias + residual.
// EPI 2: bf16 bias+gelu.       EPI 3: qkv store, V region redirected to vt.
template<int EPI>
__global__ __launch_bounds__(256) void gemm_bt(
    const bf16_t* __restrict__ A, const bf16_t* __restrict__ BT,
    const float* __restrict__ bias, const float* __restrict__ resid,
    void* __restrict__ outv, int M, int N, int K, int ldo,
    bf16_t* __restrict__ vtout)
{
    __shared__ __align__(16) unsigned char lds[49152]; // 3 x (A 8KB | B 8KB)
    const int t = threadIdx.x;
    const int w = t >> 6, l = t & 63;
    const int wr = w >> 1, wc = w & 1;
    const int lr = l & 15, lg = l >> 4;
    // T1: XCD-aware block swizzle (nwg % 8 == 0 for all launches here)
    const int nwg = gridDim.x * gridDim.y;
    int flat = blockIdx.y * gridDim.x + blockIdx.x;
    flat = (flat & 7) * (nwg >> 3) + (flat >> 3);
    const int bx = flat % gridDim.x, by = flat / gridDim.x;
    const int m0 = by * 128, n0 = bx * 128;

    const bf16_t* a_src = A  + (size_t)(m0 + (t >> 2)) * K + (t & 3) * 8;
    const bf16_t* b_src = BT + (size_t)(n0 + (t >> 2)) * K + (t & 3) * 8;
    f32x4 acc[4][4] = {};

    auto stage = [&](int kt, int buf) {
        unsigned char* d = lds + buf * 16384 + t * 16;
        async16(a_src + kt,                 d);
        async16(a_src + (size_t)64*K + kt,  d + 4096);
        async16(b_src + kt,                 d + 8192);
        async16(b_src + (size_t)64*K + kt,  d + 12288);
    };

    const int nt = K >> 5;
    stage(0, 0);
    stage(32, 1);
    asm volatile("s_waitcnt vmcnt(4)" ::: "memory");
    __builtin_amdgcn_s_barrier();

    int cur = 0;
    for (int it = 0; it < nt; ++it) {
        const bool pre = (it + 2 < nt);
        if (pre) {
            int b2 = cur + 2; if (b2 >= 3) b2 -= 3;
            stage((it + 2) << 5, b2);
        }
        const unsigned char* bufp = lds + cur * 16384;
        bf16x8 af[4], bfr[4];
#pragma unroll
        for (int n = 0; n < 4; n++)
            bfr[n] = *(const bf16x8*)(bufp + 8192 + (wc*64 + n*16 + lr)*64 + lg*16);
#pragma unroll
        for (int m = 0; m < 4; m++)
            af[m] = *(const bf16x8*)(bufp + (wr*64 + m*16 + lr)*64 + lg*16);
        __builtin_amdgcn_s_setprio(1);
#pragma unroll
        for (int m = 0; m < 4; m++)
#pragma unroll
            for (int n = 0; n < 4; n++)
                acc[m][n] = __builtin_amdgcn_mfma_f32_16x16x32_bf16(af[m], bfr[n], acc[m][n], 0, 0, 0);
        __builtin_amdgcn_s_setprio(0);
        if (it + 1 < nt) {
            asm volatile("s_waitcnt lgkmcnt(0)" ::: "memory"); // ds_reads of buf[cur] done
            if (pre) asm volatile("s_waitcnt vmcnt(4)" ::: "memory"); // drain tile it+1 only
            else     asm volatile("s_waitcnt vmcnt(0)" ::: "memory");
            __builtin_amdgcn_s_barrier();
        }
        cur = (cur + 1 == 3) ? 0 : cur + 1;
    }

#pragma unroll
    for (int m = 0; m < 4; m++) {
#pragma unroll
        for (int n = 0; n < 4; n++) {
            const int gc  = n0 + wc*64 + n*16 + lr;
            const int gr0 = m0 + wr*64 + m*16 + lg*4;
            if constexpr (EPI == 3) {
                if (gc >= 1536) {   // V output -> vt[bh][d][s], 8B vector store
                    const int hh = (gc - 1536) >> 6, dd = (gc - 1536) & 63;
                    const int bb = gr0 >> 11, ss = gr0 & 2047;
                    bf16x4 ov;
#pragma unroll
                    for (int i = 0; i < 4; i++) ov[i] = (bf16_t)acc[m][n][i];
                    *(bf16x4*)(vtout + ((size_t)(bb*NHD + hh)*64 + dd)*SEQ + ss) = ov;
                    continue;
                }
            }
#pragma unroll
            for (int i = 0; i < 4; i++) {
                const int gr = gr0 + i;
                float v = acc[m][n][i];
                if constexpr (EPI == 0 || EPI == 3) {
                    ((bf16_t*)outv)[(size_t)gr * ldo + gc] = (bf16_t)v;
                } else if constexpr (EPI == 1) {
                    ((float*)outv)[(size_t)gr * ldo + gc] =
                        v + bias[gc] + resid[(size_t)gr * ldo + gc];
                } else {
                    v += bias[gc];
                    float u = 0.7978845608028654f * (v + 0.044715f * v * v * v);
                    float g = v / (1.f + __expf(-2.f * u));   // == 0.5v(1+tanh u)
                    ((bf16_t*)outv)[(size_t)gr * ldo + gc] = (bf16_t)g;
                }
            }
        }
    }
}

// ---------------- flash attention (swapped softmax, log2 domain) --------------
// grid: (16 qtiles, 48 bh); 4 waves x 32 q-rows; K/V tiles of 64, double-buffered
// LDS staging with issue-early prefetch; 1 __syncthreads per tile.
// Scores arrive pre-scaled by 0.125*log2e (wq prescale) -> exp2 softmax.
// lsum kept as per-lane partial; cross-lane reduce deferred to epilogue.
__global__ __launch_bounds__(256) void attn_kernel(
    const bf16_t* __restrict__ qkv, const bf16_t* __restrict__ vt,
    const int* __restrict__ mask, const float* __restrict__ mbias,
    bf16_t* __restrict__ ctx)
{
    __shared__ __align__(16) unsigned char lds[49152]; // 2x(K 8KB|V 8KB) | P 4x4KB
    const int t = threadIdx.x, w = t >> 6, l = t & 63;
    const int lr = l & 15, lg = l >> 4;
    int flat = blockIdx.y * 16 + blockIdx.x;
    flat = (flat & 7) * 96 + (flat >> 3);          // nwg = 768
    const int bh = flat >> 4, qt = flat & 15;
    const int b = bh / NHD, h = bh % NHD;
    const int q0 = qt * 128 + w * 32;
    const int swz = (lr & 7) << 4;

    bf16x8 qf[2][2];
#pragma unroll
    for (int r = 0; r < 2; r++)
#pragma unroll
        for (int ks = 0; ks < 2; ks++)
            qf[r][ks] = *(const bf16x8*)(qkv + (size_t)(b*SEQ + q0 + r*16 + lr)*2304
                                         + h*64 + ks*32 + lg*8);
    int mq[2];
#pragma unroll
    for (int r = 0; r < 2; r++)
        mq[r] = mask[b*SEQ + q0 + r*16 + lr];

    float mrow[2] = { -INFINITY, -INFINITY };
    float lsum[2] = { 0.f, 0.f };           // per-lane partials (quad-reduced at end)
    f32x4 accO[2][4] = {};   // [r][dn]: q = l&15 (+r*16), d = dn*16 + lg*4 + i

    auto stage_kv = [&](int kt, int buf) {
        unsigned char* d = lds + buf * 16384;
#pragma unroll
        for (int i2 = 0; i2 < 2; i2++) {
            const int c = i2*256 + t;
            const int row = c >> 3;
            const int scol = ((c & 7) ^ (row & 7)) * 8;   // pre-swizzled source col
            async16(qkv + (size_t)(b*SEQ + kt + row)*2304 + 768 + h*64 + scol,
                    d + c*16);
            async16(vt + ((size_t)bh*64 + row)*SEQ + kt + scol,
                    d + 8192 + c*16);
        }
    };

    stage_kv(0, 0);
    __syncthreads();

    int cur = 0;
    for (int kt = 0; kt < SEQ; kt += 64) {
        if (kt + 64 < SEQ) stage_kv(kt + 64, cur ^ 1);
        f32x4 mb[4];
#pragma unroll
        for (int n = 0; n < 4; n++)
            mb[n] = *(const f32x4*)(mbias + (size_t)b*SEQ + kt + n*16 + lg*4);
        const unsigned char* bufp = lds + cur * 16384;

        // S^T = K Q^T : accS[n][r], lane q = l&15, k = n*16 + lg*4 + i
        bf16x8 kf[4][2];
#pragma unroll
        for (int n = 0; n < 4; n++)
#pragma unroll
            for (int ks = 0; ks < 2; ks++)
                kf[n][ks] = *(const bf16x8*)(bufp + (n*16 + lr)*128
                                             + ((ks*64 + lg*16) ^ swz));
        f32x4 accS[4][2] = {};
        __builtin_amdgcn_s_setprio(1);
#pragma unroll
        for (int n = 0; n < 4; n++)
#pragma unroll
            for (int r = 0; r < 2; r++)
#pragma unroll
                for (int ks = 0; ks < 2; ks++)
                    accS[n][r] = __builtin_amdgcn_mfma_f32_16x16x32_bf16(
                        kf[n][ks], qf[r][ks], accS[n][r], 0, 0, 0);
        __builtin_amdgcn_s_setprio(0);

        // in-register online softmax per r (log2 domain)
#pragma unroll
        for (int r = 0; r < 2; r++) {
            f32x4 sl[4];
#pragma unroll
            for (int n = 0; n < 4; n++)
#pragma unroll
                for (int i = 0; i < 4; i++)
                    sl[n][i] = mq[r] ? (accS[n][r][i] + mb[n][i]) : -1e9f;
            float px = -INFINITY;
#pragma unroll
            for (int n = 0; n < 4; n++)
                px = fmaxf(px, fmaxf(fmaxf(sl[n][0], sl[n][1]),
                                     fmaxf(sl[n][2], sl[n][3])));
            px = fmaxf(px, __shfl_xor(px, 16));
            px = fmaxf(px, __shfl_xor(px, 32));
            const float mold = mrow[r];
            if (!__all(px <= mold + 11.54f)) {       // T13 defer-max (8 nats)
                const float mnew = fmaxf(mold, px);
                const float sc = exp2f(mold - mnew);
                lsum[r] *= sc;
#pragma unroll
                for (int dn = 0; dn < 4; dn++) accO[r][dn] *= sc;
                mrow[r] = mnew;
            }
            const float m = mrow[r];
            float ps = 0.f;
#pragma unroll
            for (int n = 0; n < 4; n++) {
                bf16x4 pk;
#pragma unroll
                for (int i = 0; i < 4; i++) {
                    float pv = exp2f(sl[n][i] - m);
                    ps += pv;
                    pk[i] = (bf16_t)pv;
                }
                *(bf16x4*)(lds + 32768 + w*4096 + (r*16 + lr)*128
                           + ((n*32 + lg*8) ^ swz)) = pk;
            }
            lsum[r] += ps;                   // lane partial; no shfl here
        }

        // O^T += V^T P : accO[r][dn] = mfma(A=vf, B=pf)
        bf16x8 vf[4][2], pf[2][2];
#pragma unroll
        for (int dn = 0; dn < 4; dn++)
#pragma unroll
            for (int ks = 0; ks < 2; ks++)
                vf[dn][ks] = *(const bf16x8*)(bufp + 8192 + (dn*16 + lr)*128
                                              + ((ks*64 + lg*16) ^ swz));
#pragma unroll
        for (int r = 0; r < 2; r++)
#pragma unroll
            for (int ks = 0; ks < 2; ks++)
                pf[r][ks] = *(const bf16x8*)(lds + 32768 + w*4096 + (r*16 + lr)*128
                                             + ((ks*64 + lg*16) ^ swz));
        __builtin_amdgcn_s_setprio(1);
#pragma unroll
        for (int r = 0; r < 2; r++)
#pragma unroll
            for (int dn = 0; dn < 4; dn++)
#pragma unroll
                for (int ks = 0; ks < 2; ks++)
                    accO[r][dn] = __builtin_amdgcn_mfma_f32_16x16x32_bf16(
                        vf[dn][ks], pf[r][ks], accO[r][dn], 0, 0, 0);
        __builtin_amdgcn_s_setprio(0);

        __syncthreads();
        cur ^= 1;
    }

    // epilogue: quad-reduce lsum, lane-local normalize, 8B vector stores
#pragma unroll
    for (int r = 0; r < 2; r++) {
        float ls = lsum[r];
        ls += __shfl_xor(ls, 16);
        ls += __shfl_xor(ls, 32);
        const float inv = 1.f / ls;
#pragma unroll
        for (int dn = 0; dn < 4; dn++) {
            bf16x4 ov;
#pragma unroll
            for (int i = 0; i < 4; i++)
                ov[i] = (bf16_t)(accO[r][dn][i] * inv);
            *(bf16x4*)(ctx + (size_t)(b*SEQ + q0 + r*16 + lr)*HD
                       + h*64 + dn*16 + lg*4) = ov;
        }
    }
}

// ---------------- launcher ----------------------------------------------------
extern "C" void kernel_launch(void* const* d_in, const int* in_sizes, int n_in,
                              void* d_out, int out_size, void* d_ws, size_t ws_size,
                              hipStream_t stream)
{
    const float* x     = (const float*)d_in[0];
    const int*   mask  = (const int*)  d_in[1];
    const float* wq    = (const float*)d_in[2];
    const float* wk    = (const float*)d_in[3];
    const float* wv    = (const float*)d_in[4];
    const float* wo    = (const float*)d_in[5];
    const float* wo_b  = (const float*)d_in[6];
    const float* w1    = (const float*)d_in[7];
    const float* w1_b  = (const float*)d_in[8];
    const float* w2    = (const float*)d_in[9];
    const float* w2_b  = (const float*)d_in[10];
    const float* ln1_w = (const float*)d_in[11];
    const float* ln1_b = (const float*)d_in[12];
    const float* ln2_w = (const float*)d_in[13];
    const float* ln2_b = (const float*)d_in[14];

    unsigned char* ws = (unsigned char*)d_ws;
    size_t o = 0;
    auto alloc = [&](size_t bytes) {
        size_t r = o; o += (bytes + 255) & ~(size_t)255; return r;
    };
    bf16_t* wqkvT = (bf16_t*)(ws + alloc((size_t)2304*768*2));
    bf16_t* woT   = (bf16_t*)(ws + alloc((size_t)768*768*2));
    bf16_t* w1T   = (bf16_t*)(ws + alloc((size_t)3072*768*2));
    bf16_t* w2T   = (bf16_t*)(ws + alloc((size_t)768*3072*2));
    bf16_t* y     = (bf16_t*)(ws + alloc((size_t)NTOK*HD*2));   // reused as y2
    float*  x1    = (float*) (ws + alloc((size_t)NTOK*HD*4));
    bf16_t* ctx   = (bf16_t*)(ws + alloc((size_t)NTOK*HD*2));
    float*  mbias = (float*) (ws + alloc((size_t)NTOK*4));
    bf16_t* qkv   = (bf16_t*)(ws + alloc((size_t)NTOK*2304*2));
    bf16_t* vt    = (bf16_t*)(ws + alloc((size_t)48*64*SEQ*2));
    bf16_t* hbuf  = qkv; // [8192][3072] aliases qkv+vt (both dead after attention)
    (void)in_sizes; (void)n_in; (void)out_size; (void)ws_size;

    prep_kernel<<<15136,256,0,stream>>>(x, ln1_w, ln1_b, y,
                                        wq, wk, wv, wo, w1, w2, mask,
                                        wqkvT, woT, w1T, w2T, mbias);
    gemm_bt<3><<<dim3(18,64),256,0,stream>>>(y, wqkvT, nullptr, nullptr, qkv,
                                             NTOK, 2304, 768, 2304, vt);
    attn_kernel<<<dim3(16,48),256,0,stream>>>(qkv, vt, mask, mbias, ctx);
    gemm_bt<1><<<dim3(6,64),256,0,stream>>>(ctx, woT, wo_b, x, x1,
                                            NTOK, 768, 768, 768, nullptr);
    ln_kernel<<<NTOK,256,0,stream>>>(x1, ln2_w, ln2_b, y);
    gemm_bt<2><<<dim3(24,64),256,0,stream>>>(y, w1T, w1_b, nullptr, hbuf,
                                             NTOK, 3072, 768, 3072, nullptr);
    gemm_bt<1><<<dim3(6,64),256,0,stream>>>(hbuf, w2T, w2_b, x1, d_out,
                                            NTOK, 768, 3072, 768, nullptr);
}

// Round 11
// 409.897 us; speedup vs baseline: 1.0503x; 1.0503x over previous
//
#include <hip/hip_runtime.h>
#include <hip/hip_bf16.h>

#define HD   768
#define BSZ  4
#define SEQ  2048
#define NTOK (BSZ*SEQ)   // 8192
#define NHD  12
#define DKD  64

typedef __bf16 bf16_t;
typedef __bf16 bf16x8 __attribute__((ext_vector_type(8)));
typedef __bf16 bf16x4 __attribute__((ext_vector_type(4)));
typedef float  f32x4  __attribute__((ext_vector_type(4)));

__device__ __forceinline__ void async16(const void* g, void* l) {
    __builtin_amdgcn_global_load_lds(
        (const __attribute__((address_space(1))) unsigned int*)g,
        (__attribute__((address_space(3))) unsigned int*)l, 16, 0, 0);
}

// native v_exp_f32 (exp2). exp2f() would route through precise libm -- 6x cost.
__device__ __forceinline__ float fast_exp2(float x) {
    return __builtin_amdgcn_exp2f(x);
}

// ---- fused prep: LN1 (8192 blk) + 6 weight transposes (6912) + mask (32) ----
// wq is pre-scaled by 0.125*log2e so QK^T lands directly in log2 domain;
// mask bias likewise scaled by log2e (exp2 softmax).
__global__ __launch_bounds__(256) void prep_kernel(
    const float* __restrict__ x, const float* __restrict__ ln1_w,
    const float* __restrict__ ln1_b, bf16_t* __restrict__ y,
    const float* __restrict__ wq, const float* __restrict__ wk,
    const float* __restrict__ wv, const float* __restrict__ wo,
    const float* __restrict__ w1, const float* __restrict__ w2,
    const int* __restrict__ mask,
    bf16_t* __restrict__ wqkvT, bf16_t* __restrict__ woT,
    bf16_t* __restrict__ w1T, bf16_t* __restrict__ w2T,
    float* __restrict__ mb)
{
    const int bid = blockIdx.x, t = threadIdx.x;
    if (bid < 8192) {                        // ---- LN1 row ----
        const int row = bid;
        const float* xr = x + (size_t)row * HD;
        float v0 = xr[t], v1 = xr[t + 256], v2 = xr[t + 512];
        float s1 = v0 + v1 + v2;
        float s2 = v0*v0 + v1*v1 + v2*v2;
#pragma unroll
        for (int m = 1; m < 64; m <<= 1) {
            s1 += __shfl_xor(s1, m);
            s2 += __shfl_xor(s2, m);
        }
        __shared__ float red[8];
        const int w = t >> 6, l = t & 63;
        if (l == 0) { red[w] = s1; red[4 + w] = s2; }
        __syncthreads();
        s1 = red[0] + red[1] + red[2] + red[3];
        s2 = red[4] + red[5] + red[6] + red[7];
        float mean = s1 * (1.f/HD);
        float var  = fmaxf(s2 * (1.f/HD) - mean*mean, 0.f);
        float rstd = rsqrtf(var + 1e-12f);
        bf16_t* yr = y + (size_t)row * HD;
        yr[t]       = (bf16_t)(ln1_w[t]      * (v0 - mean) * rstd + ln1_b[t]);
        yr[t + 256] = (bf16_t)(ln1_w[t + 256]* (v1 - mean) * rstd + ln1_b[t + 256]);
        yr[t + 512] = (bf16_t)(ln1_w[t + 512]* (v2 - mean) * rstd + ln1_b[t + 512]);
        return;
    }
    const int wb = bid - 8192;
    if (wb >= 6912) {                        // ---- mask -> log2-domain bias ----
        const int i = (wb - 6912) * 256 + t;
        mb[i] = mask[i] ? 0.f : -1.4426950e9f;
        return;
    }
    const float* in; bf16_t* out; int K, N, ktile, ntile;
    float scale = 1.f;
    if (wb < 2304) {
        const int wsel = wb / 576, tt = wb % 576;
        const float* srcs[4] = { wq, wk, wv, wo };
        bf16_t* dsts[4] = { wqkvT, wqkvT + 768*768, wqkvT + 2*768*768, woT };
        in = srcs[wsel]; out = dsts[wsel]; K = 768; N = 768;
        if (wsel == 0) scale = 0.18033688f;  // 0.125 * log2(e)
        ktile = tt / 24; ntile = tt % 24;
    } else if (wb < 4608) {
        const int tt = wb - 2304;
        in = w1; out = w1T; K = 768; N = 3072;
        ktile = tt / 96; ntile = tt % 96;
    } else {
        const int tt = wb - 4608;
        in = w2; out = w2T; K = 3072; N = 768;
        ktile = tt / 24; ntile = tt % 24;
    }
    __shared__ float tile[32][33];
    const int k0 = ktile * 32, n0 = ntile * 32;
    const int r = t >> 5, c = t & 31;
#pragma unroll
    for (int j = 0; j < 4; j++)
        tile[r + 8*j][c] = in[(size_t)(k0 + r + 8*j) * N + n0 + c];
    __syncthreads();
#pragma unroll
    for (int j = 0; j < 4; j++)
        out[(size_t)(n0 + r + 8*j) * K + k0 + c] = (bf16_t)(tile[c][r + 8*j] * scale);
}

// ---------------- layernorm: f32 [rows][768] -> bf16 (LN2) -------------------
__global__ __launch_bounds__(256) void ln_kernel(
    const float* __restrict__ x, const float* __restrict__ gw,
    const float* __restrict__ gb, bf16_t* __restrict__ y)
{
    const int row = blockIdx.x, t = threadIdx.x;
    const float* xr = x + (size_t)row * HD;
    float v0 = xr[t], v1 = xr[t + 256], v2 = xr[t + 512];
    float s1 = v0 + v1 + v2;
    float s2 = v0*v0 + v1*v1 + v2*v2;
#pragma unroll
    for (int m = 1; m < 64; m <<= 1) {
        s1 += __shfl_xor(s1, m);
        s2 += __shfl_xor(s2, m);
    }
    __shared__ float red[8];
    const int w = t >> 6, l = t & 63;
    if (l == 0) { red[w] = s1; red[4 + w] = s2; }
    __syncthreads();
    s1 = red[0] + red[1] + red[2] + red[3];
    s2 = red[4] + red[5] + red[6] + red[7];
    float mean = s1 * (1.f/HD);
    float var  = fmaxf(s2 * (1.f/HD) - mean*mean, 0.f);
    float rstd = rsqrtf(var + 1e-12f);
    bf16_t* yr = y + (size_t)row * HD;
    yr[t]       = (bf16_t)(gw[t]      * (v0 - mean) * rstd + gb[t]);
    yr[t + 256] = (bf16_t)(gw[t + 256]* (v1 - mean) * rstd + gb[t + 256]);
    yr[t + 512] = (bf16_t)(gw[t + 512]* (v2 - mean) * rstd + gb[t + 512]);
}

// ---------------- GEMM: A[M][K] bf16 x BT[N][K] bf16 --------------------------
// depth-2 prefetch pipeline: 3 LDS buffers, counted vmcnt(4), 1 s_barrier/iter.
// EPI 0: bf16 store.           EPI 1: f32 store + bias + residual.
// EPI 2: bf16 bias+gelu.       EPI 3: qkv store, V region redirected to vt.
template<int EPI>
__global__ __launch_bounds__(256) void gemm_bt(
    const bf16_t* __restrict__ A, const bf16_t* __restrict__ BT,
    const float* __restrict__ bias, const float* __restrict__ resid,
    void* __restrict__ outv, int M, int N, int K, int ldo,
    bf16_t* __restrict__ vtout)
{
    __shared__ __align__(16) unsigned char lds[49152]; // 3 x (A 8KB | B 8KB)
    const int t = threadIdx.x;
    const int w = t >> 6, l = t & 63;
    const int wr = w >> 1, wc = w & 1;
    const int lr = l & 15, lg = l >> 4;
    // T1: XCD-aware block swizzle (nwg % 8 == 0 for all launches here)
    const int nwg = gridDim.x * gridDim.y;
    int flat = blockIdx.y * gridDim.x + blockIdx.x;
    flat = (flat & 7) * (nwg >> 3) + (flat >> 3);
    const int bx = flat % gridDim.x, by = flat / gridDim.x;
    const int m0 = by * 128, n0 = bx * 128;

    const bf16_t* a_src = A  + (size_t)(m0 + (t >> 2)) * K + (t & 3) * 8;
    const bf16_t* b_src = BT + (size_t)(n0 + (t >> 2)) * K + (t & 3) * 8;
    f32x4 acc[4][4] = {};

    auto stage = [&](int kt, int buf) {
        unsigned char* d = lds + buf * 16384 + t * 16;
        async16(a_src + kt,                 d);
        async16(a_src + (size_t)64*K + kt,  d + 4096);
        async16(b_src + kt,                 d + 8192);
        async16(b_src + (size_t)64*K + kt,  d + 12288);
    };

    const int nt = K >> 5;
    stage(0, 0);
    stage(32, 1);
    asm volatile("s_waitcnt vmcnt(4)" ::: "memory");
    __builtin_amdgcn_s_barrier();

    int cur = 0;
    for (int it = 0; it < nt; ++it) {
        const bool pre = (it + 2 < nt);
        if (pre) {
            int b2 = cur + 2; if (b2 >= 3) b2 -= 3;
            stage((it + 2) << 5, b2);
        }
        const unsigned char* bufp = lds + cur * 16384;
        bf16x8 af[4], bfr[4];
#pragma unroll
        for (int n = 0; n < 4; n++)
            bfr[n] = *(const bf16x8*)(bufp + 8192 + (wc*64 + n*16 + lr)*64 + lg*16);
#pragma unroll
        for (int m = 0; m < 4; m++)
            af[m] = *(const bf16x8*)(bufp + (wr*64 + m*16 + lr)*64 + lg*16);
        __builtin_amdgcn_s_setprio(1);
#pragma unroll
        for (int m = 0; m < 4; m++)
#pragma unroll
            for (int n = 0; n < 4; n++)
                acc[m][n] = __builtin_amdgcn_mfma_f32_16x16x32_bf16(af[m], bfr[n], acc[m][n], 0, 0, 0);
        __builtin_amdgcn_s_setprio(0);
        if (it + 1 < nt) {
            asm volatile("s_waitcnt lgkmcnt(0)" ::: "memory"); // ds_reads of buf[cur] done
            if (pre) asm volatile("s_waitcnt vmcnt(4)" ::: "memory"); // drain tile it+1 only
            else     asm volatile("s_waitcnt vmcnt(0)" ::: "memory");
            __builtin_amdgcn_s_barrier();
        }
        cur = (cur + 1 == 3) ? 0 : cur + 1;
    }

#pragma unroll
    for (int m = 0; m < 4; m++) {
#pragma unroll
        for (int n = 0; n < 4; n++) {
            const int gc  = n0 + wc*64 + n*16 + lr;
            const int gr0 = m0 + wr*64 + m*16 + lg*4;
            if constexpr (EPI == 3) {
                if (gc >= 1536) {   // V output -> vt[bh][d][s], 8B vector store
                    const int hh = (gc - 1536) >> 6, dd = (gc - 1536) & 63;
                    const int bb = gr0 >> 11, ss = gr0 & 2047;
                    bf16x4 ov;
#pragma unroll
                    for (int i = 0; i < 4; i++) ov[i] = (bf16_t)acc[m][n][i];
                    *(bf16x4*)(vtout + ((size_t)(bb*NHD + hh)*64 + dd)*SEQ + ss) = ov;
                    continue;
                }
            }
#pragma unroll
            for (int i = 0; i < 4; i++) {
                const int gr = gr0 + i;
                float v = acc[m][n][i];
                if constexpr (EPI == 0 || EPI == 3) {
                    ((bf16_t*)outv)[(size_t)gr * ldo + gc] = (bf16_t)v;
                } else if constexpr (EPI == 1) {
                    ((float*)outv)[(size_t)gr * ldo + gc] =
                        v + bias[gc] + resid[(size_t)gr * ldo + gc];
                } else {
                    v += bias[gc];
                    float u = 0.7978845608028654f * (v + 0.044715f * v * v * v);
                    float g = v / (1.f + __expf(-2.f * u));   // == 0.5v(1+tanh u)
                    ((bf16_t*)outv)[(size_t)gr * ldo + gc] = (bf16_t)g;
                }
            }
        }
    }
}

// ---------------- flash attention (swapped softmax, log2 domain) --------------
// grid: (16 qtiles, 48 bh); 4 waves x 32 q-rows; K/V tiles of 64, double-buffered
// LDS staging with issue-early prefetch; 1 __syncthreads per tile.
// Scores arrive pre-scaled by 0.125*log2e (wq prescale) -> native v_exp_f32.
// lsum kept as per-lane partial; cross-lane reduce deferred to epilogue.
__global__ __launch_bounds__(256) void attn_kernel(
    const bf16_t* __restrict__ qkv, const bf16_t* __restrict__ vt,
    const int* __restrict__ mask, const float* __restrict__ mbias,
    bf16_t* __restrict__ ctx)
{
    __shared__ __align__(16) unsigned char lds[49152]; // 2x(K 8KB|V 8KB) | P 4x4KB
    const int t = threadIdx.x, w = t >> 6, l = t & 63;
    const int lr = l & 15, lg = l >> 4;
    int flat = blockIdx.y * 16 + blockIdx.x;
    flat = (flat & 7) * 96 + (flat >> 3);          // nwg = 768
    const int bh = flat >> 4, qt = flat & 15;
    const int b = bh / NHD, h = bh % NHD;
    const int q0 = qt * 128 + w * 32;
    const int swz = (lr & 7) << 4;

    bf16x8 qf[2][2];
#pragma unroll
    for (int r = 0; r < 2; r++)
#pragma unroll
        for (int ks = 0; ks < 2; ks++)
            qf[r][ks] = *(const bf16x8*)(qkv + (size_t)(b*SEQ + q0 + r*16 + lr)*2304
                                         + h*64 + ks*32 + lg*8);
    int mq[2];
#pragma unroll
    for (int r = 0; r < 2; r++)
        mq[r] = mask[b*SEQ + q0 + r*16 + lr];

    float mrow[2] = { -INFINITY, -INFINITY };
    float lsum[2] = { 0.f, 0.f };           // per-lane partials (quad-reduced at end)
    f32x4 accO[2][4] = {};   // [r][dn]: q = l&15 (+r*16), d = dn*16 + lg*4 + i

    auto stage_kv = [&](int kt, int buf) {
        unsigned char* d = lds + buf * 16384;
#pragma unroll
        for (int i2 = 0; i2 < 2; i2++) {
            const int c = i2*256 + t;
            const int row = c >> 3;
            const int scol = ((c & 7) ^ (row & 7)) * 8;   // pre-swizzled source col
            async16(qkv + (size_t)(b*SEQ + kt + row)*2304 + 768 + h*64 + scol,
                    d + c*16);
            async16(vt + ((size_t)bh*64 + row)*SEQ + kt + scol,
                    d + 8192 + c*16);
        }
    };

    stage_kv(0, 0);
    __syncthreads();

    int cur = 0;
    for (int kt = 0; kt < SEQ; kt += 64) {
        if (kt + 64 < SEQ) stage_kv(kt + 64, cur ^ 1);
        f32x4 mb[4];
#pragma unroll
        for (int n = 0; n < 4; n++)
            mb[n] = *(const f32x4*)(mbias + (size_t)b*SEQ + kt + n*16 + lg*4);
        const unsigned char* bufp = lds + cur * 16384;

        // S^T = K Q^T : accS[n][r], lane q = l&15, k = n*16 + lg*4 + i
        bf16x8 kf[4][2];
#pragma unroll
        for (int n = 0; n < 4; n++)
#pragma unroll
            for (int ks = 0; ks < 2; ks++)
                kf[n][ks] = *(const bf16x8*)(bufp + (n*16 + lr)*128
                                             + ((ks*64 + lg*16) ^ swz));
        f32x4 accS[4][2] = {};
        __builtin_amdgcn_s_setprio(1);
#pragma unroll
        for (int n = 0; n < 4; n++)
#pragma unroll
            for (int r = 0; r < 2; r++)
#pragma unroll
                for (int ks = 0; ks < 2; ks++)
                    accS[n][r] = __builtin_amdgcn_mfma_f32_16x16x32_bf16(
                        kf[n][ks], qf[r][ks], accS[n][r], 0, 0, 0);
        __builtin_amdgcn_s_setprio(0);

        // in-register online softmax per r (log2 domain)
#pragma unroll
        for (int r = 0; r < 2; r++) {
            f32x4 sl[4];
#pragma unroll
            for (int n = 0; n < 4; n++)
#pragma unroll
                for (int i = 0; i < 4; i++)
                    sl[n][i] = mq[r] ? (accS[n][r][i] + mb[n][i]) : -1e9f;
            float px = -INFINITY;
#pragma unroll
            for (int n = 0; n < 4; n++)
                px = fmaxf(px, fmaxf(fmaxf(sl[n][0], sl[n][1]),
                                     fmaxf(sl[n][2], sl[n][3])));
            px = fmaxf(px, __shfl_xor(px, 16));
            px = fmaxf(px, __shfl_xor(px, 32));
            const float mold = mrow[r];
            if (!__all(px <= mold + 11.54f)) {       // T13 defer-max (8 nats)
                const float mnew = fmaxf(mold, px);
                const float sc = fast_exp2(mold - mnew);
                lsum[r] *= sc;
#pragma unroll
                for (int dn = 0; dn < 4; dn++) accO[r][dn] *= sc;
                mrow[r] = mnew;
            }
            const float m = mrow[r];
            float ps = 0.f;
#pragma unroll
            for (int n = 0; n < 4; n++) {
                bf16x4 pk;
#pragma unroll
                for (int i = 0; i < 4; i++) {
                    float pv = fast_exp2(sl[n][i] - m);
                    ps += pv;
                    pk[i] = (bf16_t)pv;
                }
                *(bf16x4*)(lds + 32768 + w*4096 + (r*16 + lr)*128
                           + ((n*32 + lg*8) ^ swz)) = pk;
            }
            lsum[r] += ps;                   // lane partial; no shfl here
        }

        // O^T += V^T P : accO[r][dn] = mfma(A=vf, B=pf)
        bf16x8 vf[4][2], pf[2][2];
#pragma unroll
        for (int dn = 0; dn < 4; dn++)
#pragma unroll
            for (int ks = 0; ks < 2; ks++)
                vf[dn][ks] = *(const bf16x8*)(bufp + 8192 + (dn*16 + lr)*128
                                              + ((ks*64 + lg*16) ^ swz));
#pragma unroll
        for (int r = 0; r < 2; r++)
#pragma unroll
            for (int ks = 0; ks < 2; ks++)
                pf[r][ks] = *(const bf16x8*)(lds + 32768 + w*4096 + (r*16 + lr)*128
                                             + ((ks*64 + lg*16) ^ swz));
        __builtin_amdgcn_s_setprio(1);
#pragma unroll
        for (int r = 0; r < 2; r++)
#pragma unroll
            for (int dn = 0; dn < 4; dn++)
#pragma unroll
                for (int ks = 0; ks < 2; ks++)
                    accO[r][dn] = __builtin_amdgcn_mfma_f32_16x16x32_bf16(
                        vf[dn][ks], pf[r][ks], accO[r][dn], 0, 0, 0);
        __builtin_amdgcn_s_setprio(0);

        __syncthreads();
        cur ^= 1;
    }

    // epilogue: quad-reduce lsum, lane-local normalize, 8B vector stores
#pragma unroll
    for (int r = 0; r < 2; r++) {
        float ls = lsum[r];
        ls += __shfl_xor(ls, 16);
        ls += __shfl_xor(ls, 32);
        const float inv = 1.f / ls;
#pragma unroll
        for (int dn = 0; dn < 4; dn++) {
            bf16x4 ov;
#pragma unroll
            for (int i = 0; i < 4; i++)
                ov[i] = (bf16_t)(accO[r][dn][i] * inv);
            *(bf16x4*)(ctx + (size_t)(b*SEQ + q0 + r*16 + lr)*HD
                       + h*64 + dn*16 + lg*4) = ov;
        }
    }
}

// ---------------- launcher ----------------------------------------------------
extern "C" void kernel_launch(void* const* d_in, const int* in_sizes, int n_in,
                              void* d_out, int out_size, void* d_ws, size_t ws_size,
                              hipStream_t stream)
{
    const float* x     = (const float*)d_in[0];
    const int*   mask  = (const int*)  d_in[1];
    const float* wq    = (const float*)d_in[2];
    const float* wk    = (const float*)d_in[3];
    const float* wv    = (const float*)d_in[4];
    const float* wo    = (const float*)d_in[5];
    const float* wo_b  = (const float*)d_in[6];
    const float* w1    = (const float*)d_in[7];
    const float* w1_b  = (const float*)d_in[8];
    const float* w2    = (const float*)d_in[9];
    const float* w2_b  = (const float*)d_in[10];
    const float* ln1_w = (const float*)d_in[11];
    const float* ln1_b = (const float*)d_in[12];
    const float* ln2_w = (const float*)d_in[13];
    const float* ln2_b = (const float*)d_in[14];

    unsigned char* ws = (unsigned char*)d_ws;
    size_t o = 0;
    auto alloc = [&](size_t bytes) {
        size_t r = o; o += (bytes + 255) & ~(size_t)255; return r;
    };
    bf16_t* wqkvT = (bf16_t*)(ws + alloc((size_t)2304*768*2));
    bf16_t* woT   = (bf16_t*)(ws + alloc((size_t)768*768*2));
    bf16_t* w1T   = (bf16_t*)(ws + alloc((size_t)3072*768*2));
    bf16_t* w2T   = (bf16_t*)(ws + alloc((size_t)768*3072*2));
    bf16_t* y     = (bf16_t*)(ws + alloc((size_t)NTOK*HD*2));   // reused as y2
    float*  x1    = (float*) (ws + alloc((size_t)NTOK*HD*4));
    bf16_t* ctx   = (bf16_t*)(ws + alloc((size_t)NTOK*HD*2));
    float*  mbias = (float*) (ws + alloc((size_t)NTOK*4));
    bf16_t* qkv   = (bf16_t*)(ws + alloc((size_t)NTOK*2304*2));
    bf16_t* vt    = (bf16_t*)(ws + alloc((size_t)48*64*SEQ*2));
    bf16_t* hbuf  = qkv; // [8192][3072] aliases qkv+vt (both dead after attention)
    (void)in_sizes; (void)n_in; (void)out_size; (void)ws_size;

    prep_kernel<<<15136,256,0,stream>>>(x, ln1_w, ln1_b, y,
                                        wq, wk, wv, wo, w1, w2, mask,
                                        wqkvT, woT, w1T, w2T, mbias);
    gemm_bt<3><<<dim3(18,64),256,0,stream>>>(y, wqkvT, nullptr, nullptr, qkv,
                                             NTOK, 2304, 768, 2304, vt);
    attn_kernel<<<dim3(16,48),256,0,stream>>>(qkv, vt, mask, mbias, ctx);
    gemm_bt<1><<<dim3(6,64),256,0,stream>>>(ctx, woT, wo_b, x, x1,
                                            NTOK, 768, 768, 768, nullptr);
    ln_kernel<<<NTOK,256,0,stream>>>(x1, ln2_w, ln2_b, y);
    gemm_bt<2><<<dim3(24,64),256,0,stream>>>(y, w1T, w1_b, nullptr, hbuf,
                                             NTOK, 3072, 768, 3072, nullptr);
    gemm_bt<1><<<dim3(6,64),256,0,stream>>>(hbuf, w2T, w2_b, x1, d_out,
                                            NTOK, 768, 3072, 768, nullptr);
}